// Round 23
// baseline (221.690 us; speedup 1.0000x reference)
//
#include <hip/hip_runtime.h>
#include <hip/hip_bf16.h>

using bf16 = __hip_bfloat16;
typedef __attribute__((ext_vector_type(8))) short short8;
typedef __attribute__((ext_vector_type(4))) float f32x4;

// ---------------- workspace layout (bytes) ----------------
static const size_t OFF_QP   = 0;                    // bf16 [8192][512] qp (live to end)
static const size_t OFF_KP   = (size_t)8  << 20;     // bf16 [8192][512] kp (pre-scaled; dead after scores)
static const size_t OFF_VPT  = (size_t)16 << 20;     // bf16 [8][512][1024] vpT; reused as out2 after PV
static const size_t OFF_SC   = (size_t)24 << 20;     // bf16 scores [24,40); conv partials Pc0..3 reuse [24,56)
static const size_t OFF_PA   = (size_t)40 << 20;     // bf16 PV partials Pa0 [40,48), Pa1 [48,56)
static const size_t OFF_WT   = (size_t)56 << 20;     // bf16 [4][512][512]
static const size_t OFF_CWT  = (size_t)58 << 20;     // bf16 [512][4608]
static const size_t OFF_POOL = (size_t)63 << 20;
static const size_t OFF_SE   = ((size_t)63 << 20) + 16384;
static const size_t OFF_RS   = ((size_t)63 << 20) + 32768;  // f32 [2][8192] per-half exp rowsums

// ---------------- prep: weight fp32->bf16 transposes + zero pooled ----------
__global__ __launch_bounds__(256) void prep_k(const float* __restrict__ Wq,
                                              const float* __restrict__ Wk,
                                              const float* __restrict__ Wv,
                                              const float* __restrict__ Wo,
                                              const float* __restrict__ convw,
                                              bf16* __restrict__ wT,
                                              bf16* __restrict__ cwT,
                                              float* __restrict__ pooled) {
    long idx = (long)blockIdx.x * 256 + threadIdx.x;
    if (idx < 4l * 262144) {
        int m = (int)(idx >> 18);
        int o = (int)(idx & 262143);
        int n = o >> 9, k = o & 511;
        const float* W = (m == 0) ? Wq : (m == 1) ? Wk : (m == 2) ? Wv : Wo;
        wT[idx] = __float2bfloat16(W[k * 512 + n]);
    } else if (idx < 4l * 262144 + 512l * 4608) {
        long o = idx - 4l * 262144;
        int co = (int)(o / 4608), t = (int)(o % 4608);
        cwT[o] = __float2bfloat16(convw[(long)t * 512 + co]);  // [co][tap*512+ci]
    } else if (idx < 4l * 262144 + 512l * 4608 + 4096) {
        pooled[idx - (4l * 262144 + 512l * 4608)] = 0.f;
    }
}

__device__ __forceinline__ float bf2f(unsigned short h) {
    union { unsigned int u; float f; } c;
    c.u = (unsigned int)h << 16;
    return c.f;
}

// ---------------- unified 128x128 MFMA GEMM, BK=64 (R21 proven) --------------
// OP: 1 = fused QKV projection; 2 = scores; 4 = PV split-K=2 (exp staging,
//     rowsums); 5 = Wo (sums PV partials * 1/(s0+s1))
template <int OP>
__global__ __launch_bounds__(256, 2) void gemm_k(
    const void* __restrict__ Ap0, const void* __restrict__ Ap1, const void* __restrict__ Ap2,
    int lda, long sA,
    const bf16* __restrict__ BT, int ldb, long sB,
    void* __restrict__ Cp, int ldc, long sC,
    int K, float* __restrict__ rs) {
    __shared__ bf16 As[2][128 * 64];
    __shared__ bf16 Bs[2][128 * 64];
    const int tid = threadIdx.x;
    const int l = tid & 63, w = tid >> 6;
    const int wm = w >> 1, wn = w & 1;

    const int gx = gridDim.x, gy = gridDim.y;
    const int nwg = gx * gy * gridDim.z;
    const int bid = blockIdx.x + gx * (blockIdx.y + gy * blockIdx.z);
    const int swz = (bid & 7) * (nwg >> 3) + (bid >> 3);
    const int bx = swz % gx;
    const int rem = swz / gx;
    const int by = rem % gy;
    const int zb = rem / gy;

    const int m0 = by * 128, n0 = bx * 128;
    const float isc = 0.04419417382415922f;  // 1/sqrt(512)

    int kbase = 0;
    const bf16* Ab = nullptr;
    const float* Af = nullptr;
    const bf16* Bb = BT;
    if (OP == 1) {
        Af = (const float*)(zb == 0 ? Ap0 : zb == 1 ? Ap1 : Ap2);
        Bb = BT + (long)zb * 262144;
    } else if (OP == 2) {
        Ab = (const bf16*)Ap0 + (long)zb * sA;
        Bb = BT + (long)zb * sB;
    } else if (OP == 4) {
        Ab = (const bf16*)Ap0 + (long)(zb & 7) * sA;
        Bb = BT + (long)(zb & 7) * sB;
        kbase = (zb >> 3) * 512;
    } else {  // OP == 5
        Ab = (const bf16*)Ap0;
    }

    const int fr = l & 15;
    f32x4 acc[4][4] = {};
    float esum[4] = {0.f, 0.f, 0.f, 0.f};

    float rinv_[4];
    if (OP == 5) {
#pragma unroll
        for (int i = 0; i < 4; ++i) {
            int row = m0 + ((tid + i * 256) >> 3);
            rinv_[i] = 1.0f / (rs[row] + rs[8192 + row]);
        }
    }

    short8 ar[4];
    float4 af0[4], af1[4];
    short8 br[4];

    auto stage_load = [&](int t) {
        int k0 = kbase + t * 64;
#pragma unroll
        for (int i = 0; i < 4; ++i) {
            int s = tid + i * 256;
            int row = s >> 3, c = s & 7;
            if (OP == 1) {
                const float* src = Af + (long)(m0 + row) * lda + k0 + c * 8;
                af0[i] = *(const float4*)src;
                af1[i] = *(const float4*)(src + 4);
            } else if (OP == 4) {
                union { short8 s8; unsigned short h[8]; } u, o;
                u.s8 = *(const short8*)(Ab + (long)(m0 + row) * lda + k0 + c * 8);
                float es = 0.f;
#pragma unroll
                for (int j = 0; j < 8; ++j) {
                    float e = __expf(bf2f(u.h[j]));
                    es += e;
                    union { float f; unsigned int ui; } cf;
                    cf.f = e;
                    o.h[j] = (unsigned short)(cf.ui >> 16);  // trunc ok (e>0)
                }
                esum[i] += es;
                ar[i] = o.s8;
            } else if (OP == 5) {
                union { short8 s8; unsigned short h[8]; } u0, u1, o;
                long off = (long)(m0 + row) * lda + k0 + c * 8;
                u0.s8 = *(const short8*)(Ab + off);
                u1.s8 = *(const short8*)(Ab + 4194304 + off);
#pragma unroll
                for (int j = 0; j < 8; ++j) {
                    bf16 b = __float2bfloat16((bf2f(u0.h[j]) + bf2f(u1.h[j])) * rinv_[i]);
                    o.h[j] = *(unsigned short*)&b;
                }
                ar[i] = o.s8;
            } else {
                ar[i] = *(const short8*)(Ab + (long)(m0 + row) * lda + k0 + c * 8);
            }
        }
#pragma unroll
        for (int i = 0; i < 4; ++i) {
            int s = tid + i * 256;
            int row = s >> 3, c = s & 7;
            br[i] = *(const short8*)(Bb + (long)(n0 + row) * ldb + k0 + c * 8);
        }
    };

    auto stage_write = [&](int b) {
#pragma unroll
        for (int i = 0; i < 4; ++i) {
            int s = tid + i * 256;
            int row = s >> 3, c = s & 7;
            int cx = c ^ (row & 7);
            if (OP == 1) {
                union { short8 s8; bf16 h[8]; } u;
                u.h[0] = __float2bfloat16(af0[i].x); u.h[1] = __float2bfloat16(af0[i].y);
                u.h[2] = __float2bfloat16(af0[i].z); u.h[3] = __float2bfloat16(af0[i].w);
                u.h[4] = __float2bfloat16(af1[i].x); u.h[5] = __float2bfloat16(af1[i].y);
                u.h[6] = __float2bfloat16(af1[i].z); u.h[7] = __float2bfloat16(af1[i].w);
                *(short8*)(&As[b][row * 64 + cx * 8]) = u.s8;
            } else {
                *(short8*)(&As[b][row * 64 + cx * 8]) = ar[i];
            }
        }
#pragma unroll
        for (int i = 0; i < 4; ++i) {
            int s = tid + i * 256;
            int row = s >> 3, c = s & 7;
            int cx = c ^ (row & 7);
            *(short8*)(&Bs[b][row * 64 + cx * 8]) = br[i];
        }
    };

    auto compute = [&](int b) {
#pragma unroll
        for (int h = 0; h < 2; ++h) {
            int cx = ((l >> 4) + 4 * h) ^ (fr & 7);
            short8 afr[4], bfv[4];
#pragma unroll
            for (int m = 0; m < 4; ++m) {
                int r = wm * 64 + m * 16 + fr;
                afr[m] = *(const short8*)(&As[b][r * 64 + cx * 8]);
            }
#pragma unroll
            for (int n = 0; n < 4; ++n) {
                int r = wn * 64 + n * 16 + fr;
                bfv[n] = *(const short8*)(&Bs[b][r * 64 + cx * 8]);
            }
#pragma unroll
            for (int m = 0; m < 4; ++m)
#pragma unroll
                for (int n = 0; n < 4; ++n)
                    acc[m][n] = __builtin_amdgcn_mfma_f32_16x16x32_bf16(afr[m], bfv[n], acc[m][n], 0, 0, 0);
        }
    };

    const int nt = K >> 6;
    stage_load(0);
    stage_write(0);
    int cur = 0;
    for (int t = 0; t < nt; ++t) {
        __syncthreads();
        if (t + 1 < nt) stage_load(t + 1);
        compute(cur);
        if (t + 1 < nt) stage_write(cur ^ 1);
        cur ^= 1;
    }

    if (OP == 4) {
        __syncthreads();
        float* fl = (float*)&As[0][0];
#pragma unroll
        for (int i = 0; i < 4; ++i) {
            int s = tid + i * 256;
            fl[(s >> 3) * 8 + (s & 7)] = esum[i];
        }
        __syncthreads();
        if (bx == 0 && tid < 128) {
            float s8 = 0.f;
#pragma unroll
            for (int j = 0; j < 8; ++j) s8 += fl[tid * 8 + j];
            rs[(zb >> 3) * 8192 + (zb & 7) * 1024 + m0 + tid] = s8;
        }
    }

    const int cr = (l >> 4) * 4, cc = l & 15;
#pragma unroll
    for (int m = 0; m < 4; ++m) {
#pragma unroll
        for (int n = 0; n < 4; ++n) {
#pragma unroll
            for (int j = 0; j < 4; ++j) {
                int r = m0 + wm * 64 + m * 16 + cr + j;
                int c = n0 + wn * 64 + n * 16 + cc;
                float vv = acc[m][n][j];
                if (OP == 2) {
                    ((bf16*)Cp)[(long)zb * sC + (long)r * ldc + c] = __float2bfloat16(vv);
                } else if (OP == 4) {
                    ((bf16*)Cp)[(long)(zb >> 3) * 4194304 +
                                ((long)(zb & 7) * 1024 + r) * 512 + c] = __float2bfloat16(vv);
                } else if (OP == 5) {
                    ((bf16*)Cp)[(long)r * ldc + c] = __float2bfloat16(vv);
                } else {  // OP == 1
                    if (zb == 2) {
                        ((bf16*)Cp)[(size_t)(OFF_VPT / 2) + ((long)(r >> 10) * 512 + c) * 1024 + (r & 1023)] =
                            __float2bfloat16(vv);
                    } else {
                        float sv = (zb == 1) ? vv * isc : vv;
                        ((bf16*)Cp)[(long)zb * 4194304 + (long)r * 512 + c] = __float2bfloat16(sv);
                    }
                }
            }
        }
    }
}

// ---------------- conv: 128x128, BK=32, split-K=4, 4 blocks/CU ---------------
// The untested quadrant: fat tile + 4 resident blocks (LDS 32KB). Grid
// (4,64,4)=1024 blocks. bf16 partials Pc[zb]; bias z0; fused pool atomics.
// Swizzle for 64B rows: c ^ ((row>>1)&3) (R17-verified).
__global__ __launch_bounds__(256, 4) void conv_k(
    const bf16* __restrict__ A,      // out2 NHWC [8][32][32][512]
    const bf16* __restrict__ BT,     // cwT [512][4608]
    bf16* __restrict__ P,            // partials [4][8192][512]
    const float* __restrict__ bias,
    float* __restrict__ pooled) {
    __shared__ bf16 As[2][128 * 32];
    __shared__ bf16 Bs[2][128 * 32];
    const int tid = threadIdx.x;
    const int l = tid & 63, w = tid >> 6;
    const int wm = w >> 1, wn = w & 1;

    const int gx = 4, gy = 64, nwg = 1024;
    const int bid = blockIdx.x + gx * (blockIdx.y + gy * blockIdx.z);
    const int swz = (bid & 7) * (nwg >> 3) + (bid >> 3);
    const int bx = swz % gx;
    const int rem = swz / gx;
    const int by = rem % gy;
    const int zb = rem / gy;

    const int m0 = by * 128, n0 = bx * 128;
    const int kbase = zb * 1152;  // 4608/4; 1152 % 32 == 0

    const int fr = l & 15;
    const int ck = (l >> 4) ^ ((fr >> 1) & 3);
    f32x4 acc[4][4] = {};

    int pixoff[2], hh_[2], wp_[2];
#pragma unroll
    for (int i = 0; i < 2; ++i) {
        int s = tid + i * 256;
        int row = s >> 2, c = s & 3;
        int p = m0 + row;
        int bb = p >> 10;
        hh_[i] = (p >> 5) & 31;
        wp_[i] = p & 31;
        pixoff[i] = ((bb * 32 + hh_[i]) * 32 + wp_[i]) * 512 + c * 8;
    }

    short8 ar[2], br[2];

    auto stage_load = [&](int t) {
        int k0 = kbase + t * 32;
        int tap = k0 >> 9;  // wave-uniform (32 | 512)
        int dy = tap / 3 - 1, dx = tap % 3 - 1;
        int doff = (dy * 32 + dx) * 512 + (k0 & 511);
#pragma unroll
        for (int i = 0; i < 2; ++i) {
            int h2 = hh_[i] + dy, w2 = wp_[i] + dx;
            if (((unsigned)h2 < 32u) & ((unsigned)w2 < 32u)) {
                ar[i] = *(const short8*)(A + pixoff[i] + doff);
            } else {
                short8 zz = {0, 0, 0, 0, 0, 0, 0, 0};
                ar[i] = zz;
            }
        }
#pragma unroll
        for (int i = 0; i < 2; ++i) {
            int s = tid + i * 256;
            int row = s >> 2, c = s & 3;
            br[i] = *(const short8*)(BT + (long)(n0 + row) * 4608 + k0 + c * 8);
        }
    };

    auto stage_write = [&](int b) {
#pragma unroll
        for (int i = 0; i < 2; ++i) {
            int s = tid + i * 256;
            int row = s >> 2, c = s & 3;
            int c2 = c ^ ((row >> 1) & 3);
            *(short8*)(&As[b][row * 32 + c2 * 8]) = ar[i];
        }
#pragma unroll
        for (int i = 0; i < 2; ++i) {
            int s = tid + i * 256;
            int row = s >> 2, c = s & 3;
            int c2 = c ^ ((row >> 1) & 3);
            *(short8*)(&Bs[b][row * 32 + c2 * 8]) = br[i];
        }
    };

    auto compute = [&](int b) {
        short8 af[4], bf[4];
#pragma unroll
        for (int m = 0; m < 4; ++m) {
            int r = wm * 64 + m * 16 + fr;
            af[m] = *(const short8*)(&As[b][r * 32 + ck * 8]);
        }
#pragma unroll
        for (int n = 0; n < 4; ++n) {
            int r = wn * 64 + n * 16 + fr;
            bf[n] = *(const short8*)(&Bs[b][r * 32 + ck * 8]);
        }
#pragma unroll
        for (int m = 0; m < 4; ++m)
#pragma unroll
            for (int n = 0; n < 4; ++n)
                acc[m][n] = __builtin_amdgcn_mfma_f32_16x16x32_bf16(af[m], bf[n], acc[m][n], 0, 0, 0);
    };

    const int nt = 36;  // 1152 / 32
    stage_load(0);
    stage_write(0);
    int cur = 0;
    for (int t = 0; t < nt; ++t) {
        __syncthreads();
        if (t + 1 < nt) stage_load(t + 1);
        compute(cur);
        if (t + 1 < nt) stage_write(cur ^ 1);
        cur ^= 1;
    }

    const int cr = (l >> 4) * 4, cc = l & 15;
    float csum[4] = {0.f, 0.f, 0.f, 0.f};
#pragma unroll
    for (int m = 0; m < 4; ++m) {
#pragma unroll
        for (int n = 0; n < 4; ++n) {
#pragma unroll
            for (int j = 0; j < 4; ++j) {
                int r = m0 + wm * 64 + m * 16 + cr + j;
                int c = n0 + wn * 64 + n * 16 + cc;
                float vv = acc[m][n][j];
                if (zb == 0) vv += bias[c];
                csum[n] += vv;
                P[(long)zb * 4194304 + (long)r * 512 + c] = __float2bfloat16(vv);
            }
        }
    }
    int bb = m0 >> 10;  // block within one batch (1024 % 128 == 0)
#pragma unroll
    for (int n = 0; n < 4; ++n) {
        int c = n0 + wn * 64 + n * 16 + cc;
        atomicAdd(&pooled[bb * 512 + c], csum[n] * (1.0f / 1024.0f));
    }
}

// ---------------- SE MLP: one block per batch, 512 threads -------------------
__global__ __launch_bounds__(512) void se_mlp_k(const float* __restrict__ pooled,
                                                const float* __restrict__ w1,
                                                const float* __restrict__ b1,
                                                const float* __restrict__ w2,
                                                const float* __restrict__ b2,
                                                float* __restrict__ se) {
    __shared__ float pl[512];
    __shared__ float part[4][128];
    __shared__ float hid[128];
    const int b = blockIdx.x, t = threadIdx.x;
    pl[t] = pooled[b * 512 + t];
    __syncthreads();
    const int j = t & 127, r = t >> 7;
    float acc = 0.f;
#pragma unroll 8
    for (int s = 0; s < 128; ++s) {
        int i = r * 128 + s;
        acc += pl[i] * w1[i * 128 + j];
    }
    part[r][j] = acc;
    __syncthreads();
    if (t < 128) {
        float a = part[0][t] + part[1][t] + part[2][t] + part[3][t] + b1[t];
        hid[t] = a / (1.f + __expf(-a));  // silu
    }
    __syncthreads();
    float acc2 = b2[t];
#pragma unroll 8
    for (int jj = 0; jj < 128; ++jj)
        acc2 += hid[jj] * w2[jj * 512 + t];
    se[b * 512 + t] = 1.f / (1.f + __expf(-acc2));  // sigmoid
}

// ---------------- final: SE scale (sum 4 partials) + residual + LN ----------
__global__ __launch_bounds__(256) void final_k(const bf16* __restrict__ Pc,
                                               const float* __restrict__ se,
                                               const bf16* __restrict__ qp,
                                               const float* __restrict__ g,
                                               const float* __restrict__ bta,
                                               float* __restrict__ out) {
    __shared__ float red[256];
    long p = blockIdx.x;
    int b = (int)(p >> 10);
    int t = threadIdx.x;
    float x[2];
#pragma unroll
    for (int i = 0; i < 2; ++i) {
        int c = t + i * 256;
        long o = p * 512 + c;
        float cv = __bfloat162float(Pc[o]) + __bfloat162float(Pc[4194304 + o]) +
                   __bfloat162float(Pc[2l * 4194304 + o]) + __bfloat162float(Pc[3l * 4194304 + o]);
        x[i] = __bfloat162float(qp[o]) + cv * se[b * 512 + c];
    }
    red[t] = x[0] + x[1];
    __syncthreads();
    for (int s = 128; s > 0; s >>= 1) {
        if (t < s) red[t] += red[t + s];
        __syncthreads();
    }
    float mu = red[0] * (1.0f / 512.0f);
    __syncthreads();
    float d0 = x[0] - mu, d1 = x[1] - mu;
    red[t] = d0 * d0 + d1 * d1;
    __syncthreads();
    for (int s = 128; s > 0; s >>= 1) {
        if (t < s) red[t] += red[t + s];
        __syncthreads();
    }
    float inv = rsqrtf(red[0] * (1.0f / 512.0f) + 1e-5f);
#pragma unroll
    for (int i = 0; i < 2; ++i) {
        int c = t + i * 256;
        out[p * 512 + c] = (x[i] - mu) * inv * g[c] + bta[c];
    }
}

extern "C" void kernel_launch(void* const* d_in, const int* in_sizes, int n_in,
                              void* d_out, int out_size, void* d_ws, size_t ws_size,
                              hipStream_t stream) {
    const float* q      = (const float*)d_in[0];
    const float* k      = (const float*)d_in[1];
    const float* v      = (const float*)d_in[2];
    const float* Wq     = (const float*)d_in[3];
    const float* Wk     = (const float*)d_in[4];
    const float* Wv     = (const float*)d_in[5];
    const float* Wo     = (const float*)d_in[6];
    const float* convw  = (const float*)d_in[7];
    const float* convb  = (const float*)d_in[8];
    const float* se_w1  = (const float*)d_in[9];
    const float* se_b1  = (const float*)d_in[10];
    const float* se_w2  = (const float*)d_in[11];
    const float* se_b2  = (const float*)d_in[12];
    const float* ln_g   = (const float*)d_in[13];
    const float* ln_b   = (const float*)d_in[14];

    char* ws = (char*)d_ws;
    bf16*  qp     = (bf16*)(ws + OFF_QP);
    bf16*  kp     = (bf16*)(ws + OFF_KP);
    bf16*  vpT    = (bf16*)(ws + OFF_VPT);
    bf16*  out2   = (bf16*)(ws + OFF_VPT);
    bf16*  scores = (bf16*)(ws + OFF_SC);
    bf16*  Pattn  = (bf16*)(ws + OFF_PA);
    bf16*  Pconv  = (bf16*)(ws + OFF_SC);   // [4][8192][512] over scores+Pattn (dead)
    bf16*  wT     = (bf16*)(ws + OFF_WT);
    bf16*  cwT    = (bf16*)(ws + OFF_CWT);
    float* pooled = (float*)(ws + OFF_POOL);
    float* se     = (float*)(ws + OFF_SE);
    float* rsums  = (float*)(ws + OFF_RS);

    // 1. weight transposes (fp32 -> bf16) + zero pooled
    prep_k<<<13328, 256, 0, stream>>>(Wq, Wk, Wv, Wo, convw, wT, cwT, pooled);

    // 2. fused Q/K/V projections (128x128): 768 blocks = 3/CU
    gemm_k<1><<<dim3(4, 64, 3), 256, 0, stream>>>(q, k, v, 512, 0, wT, 512, 0,
                                                  ws, 512, 0, 512, nullptr);
    // 3. scores = qf @ (kf*isc)^T (raw bf16): 512 blocks = 2/CU
    gemm_k<2><<<dim3(8, 8, 8), 256, 0, stream>>>(qp, nullptr, nullptr, 512, 1024l * 512,
                                                 kp, 512, 1024l * 512,
                                                 scores, 1024, 1024l * 1024, 512, nullptr);
    // 4. PV split-K=2: Pattn = exp(scores) @ vf halves; rsums per half
    gemm_k<4><<<dim3(4, 8, 16), 256, 0, stream>>>(scores, nullptr, nullptr, 1024, 1024l * 1024,
                                                  vpT, 1024, 512l * 1024,
                                                  Pattn, 512, 0, 512, rsums);
    // 5. out2 = ((Pa0+Pa1) * 1/(s0+s1)) @ Wo: 256 blocks
    gemm_k<5><<<dim3(4, 64, 1), 256, 0, stream>>>(Pattn, nullptr, nullptr, 512, 0,
                                                  wT + 3 * 262144, 512, 0,
                                                  out2, 512, 0, 512, rsums);
    // 6. conv: 128x128/BK=32/split-K=4, 1024 blocks = 4/CU, bf16 partials+pool
    conv_k<<<dim3(4, 64, 4), 256, 0, stream>>>(out2, cwT, Pconv, convb, pooled);
    // 7. SE MLP
    se_mlp_k<<<8, 512, 0, stream>>>(pooled, se_w1, se_b1, se_w2, se_b2, se);
    // 8. SE scale + residual + LayerNorm (sums Pc0..3)
    final_k<<<8192, 256, 0, stream>>>(Pconv, se, qp, ln_g, ln_b, (float*)d_out);
}

// Round 24
// 195.419 us; speedup vs baseline: 1.1344x; 1.1344x over previous
//
#include <hip/hip_runtime.h>
#include <hip/hip_bf16.h>

using bf16 = __hip_bfloat16;
typedef __attribute__((ext_vector_type(8))) short short8;
typedef __attribute__((ext_vector_type(4))) float f32x4;

// ---------------- workspace layout (bytes) ----------------
static const size_t OFF_QP   = 0;                    // bf16 [8192][512] qp (live to end)
static const size_t OFF_KP   = (size_t)8  << 20;     // bf16 [8192][512] kp (dead after scores)
static const size_t OFF_VPT  = (size_t)16 << 20;     // bf16 [8][512][1024] vpT; reused as out2 after PV
static const size_t OFF_SC   = (size_t)24 << 20;     // bf16 scores [24,40); convo bf16 reuses (scores dead)
static const size_t OFF_PA   = (size_t)40 << 20;     // bf16 PV partials Pa0 [40,48), Pa1 [48,56)
static const size_t OFF_WT   = (size_t)56 << 20;     // bf16 [4][512][512]
static const size_t OFF_CWT  = (size_t)58 << 20;     // bf16 [512][4608]
static const size_t OFF_POOL = (size_t)63 << 20;
static const size_t OFF_SE   = ((size_t)63 << 20) + 16384;
static const size_t OFF_RS   = ((size_t)63 << 20) + 32768;  // f32 [2][8192] per-half exp rowsums

// ---------------- prep: weight fp32->bf16 transposes + zero pooled ----------
__global__ __launch_bounds__(256) void prep_k(const float* __restrict__ Wq,
                                              const float* __restrict__ Wk,
                                              const float* __restrict__ Wv,
                                              const float* __restrict__ Wo,
                                              const float* __restrict__ convw,
                                              bf16* __restrict__ wT,
                                              bf16* __restrict__ cwT,
                                              float* __restrict__ pooled) {
    long idx = (long)blockIdx.x * 256 + threadIdx.x;
    if (idx < 4l * 262144) {
        int m = (int)(idx >> 18);
        int o = (int)(idx & 262143);
        int n = o >> 9, k = o & 511;
        const float* W = (m == 0) ? Wq : (m == 1) ? Wk : (m == 2) ? Wv : Wo;
        wT[idx] = __float2bfloat16(W[k * 512 + n]);
    } else if (idx < 4l * 262144 + 512l * 4608) {
        long o = idx - 4l * 262144;
        int co = (int)(o / 4608), t = (int)(o % 4608);
        cwT[o] = __float2bfloat16(convw[(long)t * 512 + co]);  // [co][tap*512+ci]
    } else if (idx < 4l * 262144 + 512l * 4608 + 4096) {
        pooled[idx - (4l * 262144 + 512l * 4608)] = 0.f;
    }
}

__device__ __forceinline__ float bf2f(unsigned short h) {
    union { unsigned int u; float f; } c;
    c.u = (unsigned int)h << 16;
    return c.f;
}

// ---------------- unified 128x128 MFMA GEMM, BK=64 (R21 proven, 198.9us) -----
// OP: 1 = fused QKV projection; 2 = scores; 4 = PV split-K=2 (exp staging,
//     rowsums); 5 = Wo (sums PV partials * 1/(s0+s1))
template <int OP>
__global__ __launch_bounds__(256, 2) void gemm_k(
    const void* __restrict__ Ap0, const void* __restrict__ Ap1, const void* __restrict__ Ap2,
    int lda, long sA,
    const bf16* __restrict__ BT, int ldb, long sB,
    void* __restrict__ Cp, int ldc, long sC,
    int K, float* __restrict__ rs) {
    __shared__ bf16 As[2][128 * 64];
    __shared__ bf16 Bs[2][128 * 64];
    const int tid = threadIdx.x;
    const int l = tid & 63, w = tid >> 6;
    const int wm = w >> 1, wn = w & 1;

    const int gx = gridDim.x, gy = gridDim.y;
    const int nwg = gx * gy * gridDim.z;
    const int bid = blockIdx.x + gx * (blockIdx.y + gy * blockIdx.z);
    const int swz = (bid & 7) * (nwg >> 3) + (bid >> 3);
    const int bx = swz % gx;
    const int rem = swz / gx;
    const int by = rem % gy;
    const int zb = rem / gy;

    const int m0 = by * 128, n0 = bx * 128;
    const float isc = 0.04419417382415922f;  // 1/sqrt(512)

    int kbase = 0;
    const bf16* Ab = nullptr;
    const float* Af = nullptr;
    const bf16* Bb = BT;
    if (OP == 1) {
        Af = (const float*)(zb == 0 ? Ap0 : zb == 1 ? Ap1 : Ap2);
        Bb = BT + (long)zb * 262144;
    } else if (OP == 2) {
        Ab = (const bf16*)Ap0 + (long)zb * sA;
        Bb = BT + (long)zb * sB;
    } else if (OP == 4) {
        Ab = (const bf16*)Ap0 + (long)(zb & 7) * sA;
        Bb = BT + (long)(zb & 7) * sB;
        kbase = (zb >> 3) * 512;
    } else {  // OP == 5
        Ab = (const bf16*)Ap0;
    }

    const int fr = l & 15;
    f32x4 acc[4][4] = {};
    float esum[4] = {0.f, 0.f, 0.f, 0.f};

    float rinv_[4];
    if (OP == 5) {
#pragma unroll
        for (int i = 0; i < 4; ++i) {
            int row = m0 + ((tid + i * 256) >> 3);
            rinv_[i] = 1.0f / (rs[row] + rs[8192 + row]);
        }
    }

    short8 ar[4];
    float4 af0[4], af1[4];
    short8 br[4];

    auto stage_load = [&](int t) {
        int k0 = kbase + t * 64;
#pragma unroll
        for (int i = 0; i < 4; ++i) {
            int s = tid + i * 256;
            int row = s >> 3, c = s & 7;
            if (OP == 1) {
                const float* src = Af + (long)(m0 + row) * lda + k0 + c * 8;
                af0[i] = *(const float4*)src;
                af1[i] = *(const float4*)(src + 4);
            } else if (OP == 4) {
                union { short8 s8; unsigned short h[8]; } u, o;
                u.s8 = *(const short8*)(Ab + (long)(m0 + row) * lda + k0 + c * 8);
                float es = 0.f;
#pragma unroll
                for (int j = 0; j < 8; ++j) {
                    float e = __expf(bf2f(u.h[j]));
                    es += e;
                    union { float f; unsigned int ui; } cf;
                    cf.f = e;
                    o.h[j] = (unsigned short)(cf.ui >> 16);  // trunc ok (e>0)
                }
                esum[i] += es;
                ar[i] = o.s8;
            } else if (OP == 5) {
                union { short8 s8; unsigned short h[8]; } u0, u1, o;
                long off = (long)(m0 + row) * lda + k0 + c * 8;
                u0.s8 = *(const short8*)(Ab + off);
                u1.s8 = *(const short8*)(Ab + 4194304 + off);
#pragma unroll
                for (int j = 0; j < 8; ++j) {
                    bf16 b = __float2bfloat16((bf2f(u0.h[j]) + bf2f(u1.h[j])) * rinv_[i]);
                    o.h[j] = *(unsigned short*)&b;
                }
                ar[i] = o.s8;
            } else {
                ar[i] = *(const short8*)(Ab + (long)(m0 + row) * lda + k0 + c * 8);
            }
        }
#pragma unroll
        for (int i = 0; i < 4; ++i) {
            int s = tid + i * 256;
            int row = s >> 3, c = s & 7;
            br[i] = *(const short8*)(Bb + (long)(n0 + row) * ldb + k0 + c * 8);
        }
    };

    auto stage_write = [&](int b) {
#pragma unroll
        for (int i = 0; i < 4; ++i) {
            int s = tid + i * 256;
            int row = s >> 3, c = s & 7;
            int cx = c ^ (row & 7);
            if (OP == 1) {
                union { short8 s8; bf16 h[8]; } u;
                u.h[0] = __float2bfloat16(af0[i].x); u.h[1] = __float2bfloat16(af0[i].y);
                u.h[2] = __float2bfloat16(af0[i].z); u.h[3] = __float2bfloat16(af0[i].w);
                u.h[4] = __float2bfloat16(af1[i].x); u.h[5] = __float2bfloat16(af1[i].y);
                u.h[6] = __float2bfloat16(af1[i].z); u.h[7] = __float2bfloat16(af1[i].w);
                *(short8*)(&As[b][row * 64 + cx * 8]) = u.s8;
            } else {
                *(short8*)(&As[b][row * 64 + cx * 8]) = ar[i];
            }
        }
#pragma unroll
        for (int i = 0; i < 4; ++i) {
            int s = tid + i * 256;
            int row = s >> 3, c = s & 7;
            int cx = c ^ (row & 7);
            *(short8*)(&Bs[b][row * 64 + cx * 8]) = br[i];
        }
    };

    auto compute = [&](int b) {
#pragma unroll
        for (int h = 0; h < 2; ++h) {
            int cx = ((l >> 4) + 4 * h) ^ (fr & 7);
            short8 afr[4], bfv[4];
#pragma unroll
            for (int m = 0; m < 4; ++m) {
                int r = wm * 64 + m * 16 + fr;
                afr[m] = *(const short8*)(&As[b][r * 64 + cx * 8]);
            }
#pragma unroll
            for (int n = 0; n < 4; ++n) {
                int r = wn * 64 + n * 16 + fr;
                bfv[n] = *(const short8*)(&Bs[b][r * 64 + cx * 8]);
            }
#pragma unroll
            for (int m = 0; m < 4; ++m)
#pragma unroll
                for (int n = 0; n < 4; ++n)
                    acc[m][n] = __builtin_amdgcn_mfma_f32_16x16x32_bf16(afr[m], bfv[n], acc[m][n], 0, 0, 0);
        }
    };

    const int nt = K >> 6;
    stage_load(0);
    stage_write(0);
    int cur = 0;
    for (int t = 0; t < nt; ++t) {
        __syncthreads();
        if (t + 1 < nt) stage_load(t + 1);
        compute(cur);
        if (t + 1 < nt) stage_write(cur ^ 1);
        cur ^= 1;
    }

    if (OP == 4) {
        __syncthreads();
        float* fl = (float*)&As[0][0];
#pragma unroll
        for (int i = 0; i < 4; ++i) {
            int s = tid + i * 256;
            fl[(s >> 3) * 8 + (s & 7)] = esum[i];
        }
        __syncthreads();
        if (bx == 0 && tid < 128) {
            float s8 = 0.f;
#pragma unroll
            for (int j = 0; j < 8; ++j) s8 += fl[tid * 8 + j];
            rs[(zb >> 3) * 8192 + (zb & 7) * 1024 + m0 + tid] = s8;
        }
    }

    const int cr = (l >> 4) * 4, cc = l & 15;
#pragma unroll
    for (int m = 0; m < 4; ++m) {
#pragma unroll
        for (int n = 0; n < 4; ++n) {
#pragma unroll
            for (int j = 0; j < 4; ++j) {
                int r = m0 + wm * 64 + m * 16 + cr + j;
                int c = n0 + wn * 64 + n * 16 + cc;
                float vv = acc[m][n][j];
                if (OP == 2) {
                    ((bf16*)Cp)[(long)zb * sC + (long)r * ldc + c] = __float2bfloat16(vv);
                } else if (OP == 4) {
                    ((bf16*)Cp)[(long)(zb >> 3) * 4194304 +
                                ((long)(zb & 7) * 1024 + r) * 512 + c] = __float2bfloat16(vv);
                } else if (OP == 5) {
                    ((bf16*)Cp)[(long)r * ldc + c] = __float2bfloat16(vv);
                } else {  // OP == 1
                    if (zb == 2) {
                        ((bf16*)Cp)[(size_t)(OFF_VPT / 2) + ((long)(r >> 10) * 512 + c) * 1024 + (r & 1023)] =
                            __float2bfloat16(vv);
                    } else {
                        float sv = (zb == 1) ? vv * isc : vv;
                        ((bf16*)Cp)[(long)zb * 4194304 + (long)r * 512 + c] = __float2bfloat16(sv);
                    }
                }
            }
        }
    }
}

// ---------------- conv: 128x64, BK=64, 4-deep prefetch (R15 measured-best) ---
// bf16 direct out + fused bias + global-avg-pool. Grid (8,64,1)=512 blocks.
__global__ __launch_bounds__(256, 2) void conv_k(
    const bf16* __restrict__ A,      // out2 NHWC [8][32][32][512]
    const bf16* __restrict__ BT,     // cwT [512][4608]
    bf16* __restrict__ C,            // convo [8192][512]
    const float* __restrict__ bias,
    float* __restrict__ pooled) {
    __shared__ bf16 As[2][128 * 64];
    __shared__ bf16 Bs[2][64 * 64];
    const int tid = threadIdx.x;
    const int l = tid & 63, w = tid >> 6;
    const int wm = w >> 1, wn = w & 1;

    const int gx = 8, gy = 64, nwg = 512;
    const int bid = blockIdx.x + gx * blockIdx.y;
    const int swz = (bid & 7) * (nwg >> 3) + (bid >> 3);
    const int bx = swz % gx;
    const int by = swz / gx;

    const int m0 = by * 128, n0 = bx * 64;
    const int fr = l & 15;
    f32x4 acc[4][2] = {};

    int pixoff[4], hh_[4], wp_[4];
#pragma unroll
    for (int i = 0; i < 4; ++i) {
        int s = tid + i * 256;
        int row = s >> 3, c = s & 7;
        int p = m0 + row;
        int bb = p >> 10;
        hh_[i] = (p >> 5) & 31;
        wp_[i] = p & 31;
        pixoff[i] = ((bb * 32 + hh_[i]) * 32 + wp_[i]) * 512 + c * 8;
    }

    struct SR { short8 ar[4]; short8 br[2]; };
    SR S0, S1, S2, S3;

    auto stage_load = [&](int t, SR& S) {
        int k0 = t * 64;
        int tap = k0 >> 9;  // wave-uniform
        int dy = tap / 3 - 1, dx = tap % 3 - 1;
        int doff = (dy * 32 + dx) * 512 + (k0 & 511);
#pragma unroll
        for (int i = 0; i < 4; ++i) {
            int h2 = hh_[i] + dy, w2 = wp_[i] + dx;
            if (((unsigned)h2 < 32u) & ((unsigned)w2 < 32u)) {
                S.ar[i] = *(const short8*)(A + pixoff[i] + doff);
            } else {
                short8 zz = {0, 0, 0, 0, 0, 0, 0, 0};
                S.ar[i] = zz;
            }
        }
#pragma unroll
        for (int i = 0; i < 2; ++i) {
            int s = tid + i * 256;
            int row = s >> 3, c = s & 7;
            S.br[i] = *(const short8*)(BT + (long)(n0 + row) * 4608 + k0 + c * 8);
        }
    };

    auto stage_write = [&](int b, SR& S) {
#pragma unroll
        for (int i = 0; i < 4; ++i) {
            int s = tid + i * 256;
            int row = s >> 3, c = s & 7;
            int cx = c ^ (row & 7);
            *(short8*)(&As[b][row * 64 + cx * 8]) = S.ar[i];
        }
#pragma unroll
        for (int i = 0; i < 2; ++i) {
            int s = tid + i * 256;
            int row = s >> 3, c = s & 7;
            int cx = c ^ (row & 7);
            *(short8*)(&Bs[b][row * 64 + cx * 8]) = S.br[i];
        }
    };

    auto compute = [&](int b) {
#pragma unroll
        for (int h = 0; h < 2; ++h) {
            int cx = ((l >> 4) + 4 * h) ^ (fr & 7);
            short8 afr[4], bfv[2];
#pragma unroll
            for (int m = 0; m < 4; ++m) {
                int r = wm * 64 + m * 16 + fr;
                afr[m] = *(const short8*)(&As[b][r * 64 + cx * 8]);
            }
#pragma unroll
            for (int n = 0; n < 2; ++n) {
                int r = wn * 32 + n * 16 + fr;
                bfv[n] = *(const short8*)(&Bs[b][r * 64 + cx * 8]);
            }
#pragma unroll
            for (int m = 0; m < 4; ++m)
#pragma unroll
                for (int n = 0; n < 2; ++n)
                    acc[m][n] = __builtin_amdgcn_mfma_f32_16x16x32_bf16(afr[m], bfv[n], acc[m][n], 0, 0, 0);
        }
    };

    const int nt = 72;  // 4608/64, divisible by 4
    stage_load(0, S0);
    stage_load(1, S1);
    stage_load(2, S2);
    stage_load(3, S3);
    stage_write(0, S0);
    for (int t = 0; t < nt; t += 4) {
        __syncthreads();
        if (t + 4 < nt) stage_load(t + 4, S0);
        compute(0);
        stage_write(1, S1);
        __syncthreads();
        if (t + 5 < nt) stage_load(t + 5, S1);
        compute(1);
        stage_write(0, S2);
        __syncthreads();
        if (t + 6 < nt) stage_load(t + 6, S2);
        compute(0);
        stage_write(1, S3);
        __syncthreads();
        if (t + 7 < nt) stage_load(t + 7, S3);
        compute(1);
        if (t + 4 < nt) stage_write(0, S0);
    }

    const int cr = (l >> 4) * 4, cc = l & 15;
    float csum[2] = {0.f, 0.f};
#pragma unroll
    for (int m = 0; m < 4; ++m) {
#pragma unroll
        for (int n = 0; n < 2; ++n) {
#pragma unroll
            for (int j = 0; j < 4; ++j) {
                int r = m0 + wm * 64 + m * 16 + cr + j;
                int c = n0 + wn * 32 + n * 16 + cc;
                float vv = acc[m][n][j] + bias[c];
                csum[n] += vv;
                C[(long)r * 512 + c] = __float2bfloat16(vv);
            }
        }
    }
    int bb = m0 >> 10;  // block within one batch (1024 % 128 == 0)
#pragma unroll
    for (int n = 0; n < 2; ++n) {
        int c = n0 + wn * 32 + n * 16 + cc;
        atomicAdd(&pooled[bb * 512 + c], csum[n] * (1.0f / 1024.0f));
    }
}

// ---------------- SE MLP: one block per batch, 512 threads -------------------
__global__ __launch_bounds__(512) void se_mlp_k(const float* __restrict__ pooled,
                                                const float* __restrict__ w1,
                                                const float* __restrict__ b1,
                                                const float* __restrict__ w2,
                                                const float* __restrict__ b2,
                                                float* __restrict__ se) {
    __shared__ float pl[512];
    __shared__ float part[4][128];
    __shared__ float hid[128];
    const int b = blockIdx.x, t = threadIdx.x;
    pl[t] = pooled[b * 512 + t];
    __syncthreads();
    const int j = t & 127, r = t >> 7;
    float acc = 0.f;
#pragma unroll 8
    for (int s = 0; s < 128; ++s) {
        int i = r * 128 + s;
        acc += pl[i] * w1[i * 128 + j];
    }
    part[r][j] = acc;
    __syncthreads();
    if (t < 128) {
        float a = part[0][t] + part[1][t] + part[2][t] + part[3][t] + b1[t];
        hid[t] = a / (1.f + __expf(-a));  // silu
    }
    __syncthreads();
    float acc2 = b2[t];
#pragma unroll 8
    for (int jj = 0; jj < 128; ++jj)
        acc2 += hid[jj] * w2[jj * 512 + t];
    se[b * 512 + t] = 1.f / (1.f + __expf(-acc2));  // sigmoid
}

// ---------------- final: SE scale + residual + LayerNorm -> f32 out ---------
__global__ __launch_bounds__(256) void final_k(const bf16* __restrict__ convo,
                                               const float* __restrict__ se,
                                               const bf16* __restrict__ qp,
                                               const float* __restrict__ g,
                                               const float* __restrict__ bta,
                                               float* __restrict__ out) {
    __shared__ float red[256];
    long p = blockIdx.x;
    int b = (int)(p >> 10);
    int t = threadIdx.x;
    float x[2];
#pragma unroll
    for (int i = 0; i < 2; ++i) {
        int c = t + i * 256;
        long o = p * 512 + c;
        x[i] = __bfloat162float(qp[o]) + __bfloat162float(convo[o]) * se[b * 512 + c];
    }
    red[t] = x[0] + x[1];
    __syncthreads();
    for (int s = 128; s > 0; s >>= 1) {
        if (t < s) red[t] += red[t + s];
        __syncthreads();
    }
    float mu = red[0] * (1.0f / 512.0f);
    __syncthreads();
    float d0 = x[0] - mu, d1 = x[1] - mu;
    red[t] = d0 * d0 + d1 * d1;
    __syncthreads();
    for (int s = 128; s > 0; s >>= 1) {
        if (t < s) red[t] += red[t + s];
        __syncthreads();
    }
    float inv = rsqrtf(red[0] * (1.0f / 512.0f) + 1e-5f);
#pragma unroll
    for (int i = 0; i < 2; ++i) {
        int c = t + i * 256;
        out[p * 512 + c] = (x[i] - mu) * inv * g[c] + bta[c];
    }
}

extern "C" void kernel_launch(void* const* d_in, const int* in_sizes, int n_in,
                              void* d_out, int out_size, void* d_ws, size_t ws_size,
                              hipStream_t stream) {
    const float* q      = (const float*)d_in[0];
    const float* k      = (const float*)d_in[1];
    const float* v      = (const float*)d_in[2];
    const float* Wq     = (const float*)d_in[3];
    const float* Wk     = (const float*)d_in[4];
    const float* Wv     = (const float*)d_in[5];
    const float* Wo     = (const float*)d_in[6];
    const float* convw  = (const float*)d_in[7];
    const float* convb  = (const float*)d_in[8];
    const float* se_w1  = (const float*)d_in[9];
    const float* se_b1  = (const float*)d_in[10];
    const float* se_w2  = (const float*)d_in[11];
    const float* se_b2  = (const float*)d_in[12];
    const float* ln_g   = (const float*)d_in[13];
    const float* ln_b   = (const float*)d_in[14];

    char* ws = (char*)d_ws;
    bf16*  qp     = (bf16*)(ws + OFF_QP);
    bf16*  kp     = (bf16*)(ws + OFF_KP);
    bf16*  vpT    = (bf16*)(ws + OFF_VPT);
    bf16*  out2   = (bf16*)(ws + OFF_VPT);
    bf16*  scores = (bf16*)(ws + OFF_SC);
    bf16*  convo  = (bf16*)(ws + OFF_SC);   // reuse scores (dead after PV)
    bf16*  Pattn  = (bf16*)(ws + OFF_PA);
    bf16*  wT     = (bf16*)(ws + OFF_WT);
    bf16*  cwT    = (bf16*)(ws + OFF_CWT);
    float* pooled = (float*)(ws + OFF_POOL);
    float* se     = (float*)(ws + OFF_SE);
    float* rsums  = (float*)(ws + OFF_RS);

    // 1. weight transposes (fp32 -> bf16) + zero pooled
    prep_k<<<13328, 256, 0, stream>>>(Wq, Wk, Wv, Wo, convw, wT, cwT, pooled);

    // 2. fused Q/K/V projections (128x128): 768 blocks = 3/CU
    gemm_k<1><<<dim3(4, 64, 3), 256, 0, stream>>>(q, k, v, 512, 0, wT, 512, 0,
                                                  ws, 512, 0, 512, nullptr);
    // 3. scores = qf @ (kf*isc)^T (raw bf16): 512 blocks = 2/CU
    gemm_k<2><<<dim3(8, 8, 8), 256, 0, stream>>>(qp, nullptr, nullptr, 512, 1024l * 512,
                                                 kp, 512, 1024l * 512,
                                                 scores, 1024, 1024l * 1024, 512, nullptr);
    // 4. PV split-K=2: Pattn = exp(scores) @ vf halves; rsums per half
    gemm_k<4><<<dim3(4, 8, 16), 256, 0, stream>>>(scores, nullptr, nullptr, 1024, 1024l * 1024,
                                                  vpT, 1024, 512l * 1024,
                                                  Pattn, 512, 0, 512, rsums);
    // 5. out2 = ((Pa0+Pa1) * 1/(s0+s1)) @ Wo: 256 blocks
    gemm_k<5><<<dim3(4, 64, 1), 256, 0, stream>>>(Pattn, nullptr, nullptr, 512, 0,
                                                  wT + 3 * 262144, 512, 0,
                                                  out2, 512, 0, 512, rsums);
    // 6. conv 3x3 SAME: 128x64/BK=64 (measured-best) + fused bias/pool
    conv_k<<<dim3(8, 64, 1), 256, 0, stream>>>(out2, cwT, convo, convb, pooled);
    // 7. SE MLP
    se_mlp_k<<<8, 512, 0, stream>>>(pooled, se_w1, se_b1, se_w2, se_b2, se);
    // 8. SE scale + residual + LayerNorm
    final_k<<<8192, 256, 0, stream>>>(convo, se, qp, ln_g, ln_b, (float*)d_out);
}